// Round 1
// baseline (295.917 us; speedup 1.0000x reference)
//
#include <hip/hip_runtime.h>
#include <hip/hip_bf16.h>

typedef unsigned short u16;
typedef __attribute__((ext_vector_type(8))) short bf16x8;
typedef __attribute__((ext_vector_type(4))) float f32x4;
typedef __attribute__((ext_vector_type(4))) unsigned short u16x4;

#define EMB 1024
#define SEQ 2048
#define NH 16
#define HD 64

// ws element offsets (bf16 elems)
#define OFF_WT   0u          // [3072][1024]  WqT|WkT|WvT (bf16)
#define OFF_WOT  3145728u    // [1024][1024]  WoT (bf16)
#define OFF_Q    4194304u    // [64][64][2048]  (bh, d, s)  Q^T, pre-scaled by 0.125*log2e
#define OFF_K    12582912u   // [64][2048][64]  (bh, s, d)
#define OFF_VT   20971520u   // [64][64][2048]  (bh, d, s)  V transposed
#define OFF_OC   29360128u   // [8192][1024]   attn output, concat layout
// Xb (x in bf16) lives in d_out until gemm_out overwrites it (stream-ordered).

#define QSCALE 0.1803368801111f   // 0.125 * log2(e)

__device__ __forceinline__ u16 f2bf(float f) {
    unsigned int x; __builtin_memcpy(&x, &f, 4);
    unsigned int r = x + 0x7fffu + ((x >> 16) & 1u);   // RNE
    return (u16)(r >> 16);
}

#if defined(__has_builtin) && __has_builtin(__builtin_amdgcn_cvt_pk_bf16_f32)
typedef __attribute__((ext_vector_type(2))) __bf16 bfv2;
__device__ __forceinline__ unsigned int pkbf(float a, float b) {
    bfv2 v = __builtin_amdgcn_cvt_pk_bf16_f32(a, b);   // elem0 = a (low half)
    unsigned int u; __builtin_memcpy(&u, &v, 4); return u;
}
#else
__device__ __forceinline__ unsigned int pkbf(float a, float b) {
    return (unsigned)f2bf(a) | ((unsigned)f2bf(b) << 16);
}
#endif

// bare v_exp_f32 (no overflow/denorm guards; scores are |x| < ~30 << 126)
#if defined(__has_builtin) && __has_builtin(__builtin_amdgcn_exp2f)
__device__ __forceinline__ float exp2fast(float x) { return __builtin_amdgcn_exp2f(x); }
#else
__device__ __forceinline__ float exp2fast(float x) { return __builtin_exp2f(x); }
#endif

__device__ __forceinline__ void gld_lds16(const void* gsrc, void* ldst) {
    void* g = const_cast<void*>(gsrc);
    __builtin_amdgcn_global_load_lds((__attribute__((address_space(1))) void*)g,
                                     (__attribute__((address_space(3))) void*)ldst,
                                     16, 0, 0);
}

// ---------------------------------------------------------------------------
// Kernel 0: convert x (fp32) -> Xb (bf16), 4 elems/thread.
// ---------------------------------------------------------------------------
__global__ __launch_bounds__(256) void convert_x(
    const float* __restrict__ x, u16* __restrict__ xb)
{
    int i = (blockIdx.x * 256 + threadIdx.x) * 4;
    float4 v = *(const float4*)&x[i];
    uint2 o = { pkbf(v.x, v.y), pkbf(v.z, v.w) };
    *(uint2*)&xb[i] = o;
}

// ---------------------------------------------------------------------------
// Kernel 1: transpose the four 1024x1024 fp32 weights into ws as bf16.
// ---------------------------------------------------------------------------
__global__ __launch_bounds__(256) void transpose_w(
    const float* __restrict__ W0, const float* __restrict__ W1,
    const float* __restrict__ W2, const float* __restrict__ W3,
    u16* __restrict__ ws)
{
    __shared__ u16 tile[64 * 65];
    const float* src = blockIdx.z == 0 ? W0 : blockIdx.z == 1 ? W1 : blockIdx.z == 2 ? W2 : W3;
    u16* dst = ws + (blockIdx.z < 3 ? (unsigned)blockIdx.z * 1048576u : OFF_WOT);
    const int k0 = blockIdx.x * 64, n0 = blockIdx.y * 64;
    const int t = threadIdx.x;
    #pragma unroll
    for (int i = 0; i < 16; i++) {
        int idx = i * 256 + t; int r = idx >> 6, c = idx & 63;
        tile[c * 65 + r] = f2bf(src[(k0 + r) * EMB + n0 + c]);
    }
    __syncthreads();
    #pragma unroll
    for (int i = 0; i < 16; i++) {
        int idx = i * 256 + t; int r = idx >> 6, c = idx & 63;
        dst[(n0 + r) * EMB + k0 + c] = tile[r * 65 + c];
    }
}

// ---------------------------------------------------------------------------
// Kernel 2: fused QKV projection.  C[8192,3072] = Xb[8192,1024] @ WT^T (+bias)
// Q segment: scaled by QSCALE and stored TRANSPOSED [bh][d][s] (packed u2).
// V segment: stored transposed [bh][d][s].  K: [bh][s][d] (flash A-frags).
// ---------------------------------------------------------------------------
__global__ __launch_bounds__(256) void gemm_qkv(
    const u16* __restrict__ X, const u16* __restrict__ WT,
    const float* __restrict__ bq, const float* __restrict__ bk, const float* __restrict__ bv,
    u16* __restrict__ Qt, u16* __restrict__ Ko, u16* __restrict__ Vt)
{
    __shared__ u16 Al[128 * 32];
    __shared__ u16 Bl[128 * 32];
    const int t = threadIdx.x, lane = t & 63, w = t >> 6;
    const int quad = lane >> 4, l15 = lane & 15;
    const int wr = w >> 1, wc = w & 1;
    const int m0 = blockIdx.x * 128, n0 = blockIdx.y * 128;
    const f32x4 fzero = {0.f, 0.f, 0.f, 0.f};

    f32x4 acc[4][4];
    #pragma unroll
    for (int i = 0; i < 4; i++)
        #pragma unroll
        for (int j = 0; j < 4; j++) acc[i][j] = fzero;

    for (int kt = 0; kt < 32; ++kt) {
        #pragma unroll
        for (int r = 0; r < 2; r++) {
            int g = r * 256 + t; int row = g >> 2, cw = g & 3;
            int sc = (cw ^ ((row >> 1) & 3)) * 8;
            gld_lds16(X  + (size_t)(m0 + row) * EMB + kt * 32 + sc, &Al[g * 8]);
            gld_lds16(WT + (size_t)(n0 + row) * EMB + kt * 32 + sc, &Bl[g * 8]);
        }
        __syncthreads();
        bf16x8 af[4], bfr[4];
        #pragma unroll
        for (int i = 0; i < 4; i++) {
            int rowA = wr * 64 + i * 16 + l15;
            af[i] = *(const bf16x8*)&Al[rowA * 32 + ((quad ^ ((rowA >> 1) & 3)) * 8)];
        }
        #pragma unroll
        for (int j = 0; j < 4; j++) {
            int rowB = wc * 64 + j * 16 + l15;
            bfr[j] = *(const bf16x8*)&Bl[rowB * 32 + ((quad ^ ((rowB >> 1) & 3)) * 8)];
        }
        #pragma unroll
        for (int i = 0; i < 4; i++)
            #pragma unroll
            for (int j = 0; j < 4; j++)
                acc[i][j] = __builtin_amdgcn_mfma_f32_16x16x32_bf16(af[i], bfr[j], acc[i][j], 0, 0, 0);
        __syncthreads();
    }

    const int seg = n0 >> 10;
    const float* bias = seg == 0 ? bq : (seg == 1 ? bk : bv);
    #pragma unroll
    for (int j = 0; j < 4; j++) {
        int n = n0 + wc * 64 + j * 16 + l15;
        int nn = n & 1023;
        float bvl = bias[nn];
        int h = nn >> 6, d = nn & 63;
        #pragma unroll
        for (int i = 0; i < 4; i++) {
            int m = m0 + wr * 64 + i * 16 + quad * 4;
            int b = m >> 11, s = m & 2047;
            if (seg == 0) {          // Q^T, scaled: [bh][d][s], s packed over regs
                uint2 pp = { pkbf((acc[i][j][0] + bvl) * QSCALE, (acc[i][j][1] + bvl) * QSCALE),
                             pkbf((acc[i][j][2] + bvl) * QSCALE, (acc[i][j][3] + bvl) * QSCALE) };
                *(uint2*)&Qt[(size_t)((b * NH + h) * HD + d) * SEQ + s] = pp;
            } else if (seg == 2) {   // V^T: [bh][d][s]
                uint2 pp = { pkbf(acc[i][j][0] + bvl, acc[i][j][1] + bvl),
                             pkbf(acc[i][j][2] + bvl, acc[i][j][3] + bvl) };
                *(uint2*)&Vt[(size_t)((b * NH + h) * HD + d) * SEQ + s] = pp;
            } else {                 // K: [bh][s][d]
                size_t base = (size_t)((b * NH + h) * SEQ + s) * HD + d;
                #pragma unroll
                for (int r = 0; r < 4; r++) Ko[base + (size_t)r * HD] = f2bf(acc[i][j][r] + bvl);
            }
        }
    }
}

// ---------------------------------------------------------------------------
// Kernel 3: flash attention, transposed-score + max-free softmax.
// Round-0 restructure: T3-lite single-barrier pipeline.
//  - K/V LDS double-buffered; gld_lds for kt+1 issued BEFORE compute of kt;
//    one raw s_barrier + vmcnt(0) per kt (was: 2x __syncthreads with full
//    drain right after the loads -> staging serialized with compute).
//  - Per-i fused QK->exp->PV (ak+av both live; VGPR ~230 < 256 @ 2 waves/SIMD),
//    P buffer 2-deep by i parity: LDS 52KB -> 50KB despite K/V doubling.
//  - s_setprio(1) around MFMA clusters (m191: +4-7% on attn).
// ---------------------------------------------------------------------------
__global__ __launch_bounds__(256, 2) void flash_attn(
    const u16* __restrict__ Q, const u16* __restrict__ K,
    const u16* __restrict__ VT, u16* __restrict__ Oc)
{
    __shared__ u16 Kl[2][64 * 64];     // [buf][key][d], chunk-swizzled
    __shared__ u16 Vl[2][64 * 64];     // [buf][d][key], chunk-swizzled
    __shared__ u16 Pl[4][2][16 * 72];  // per-wave P^T, 2-deep by i parity, pad 72
    const int t = threadIdx.x, lane = t & 63, w = t >> 6;
    const int quad = lane >> 4, l15 = lane & 15;
    const int a7 = l15 & 7;
    const int bh = blockIdx.y;
    const int b = bh >> 4, h = bh & 15;
    const int q0 = blockIdx.x * 256 + w * 64;
    const u16* Qtb = Q + (size_t)bh * HD * SEQ;    // Q^T [d][s]
    const u16* Kb  = K + (size_t)bh * SEQ * HD;
    const u16* Vb  = VT + (size_t)bh * HD * SEQ;
    const f32x4 fzero = {0.f, 0.f, 0.f, 0.f};

    // fragment element-offsets within one K/V buffer (f-invariant: (f*16+l15)&7 == l15&7)
    const int kf0 = l15 * 64 + ((quad ^ a7) * 8);
    const int kf1 = l15 * 64 + (((4 + quad) ^ a7) * 8);
    u16* pww = &Pl[w][0][l15 * 72 + quad * 4];         // write base (+ par + f*16)
    const u16* pwr = &Pl[w][0][l15 * 72 + quad * 8];   // read base  (+ par + c*32)

    // constant all-ones A fragment (bf16 1.0 = 0x3F80)
    bf16x8 ones;
    #pragma unroll
    for (int j = 0; j < 8; j++) ones[j] = (short)0x3F80;

    // Q as B-operand fragments (persistent): B[k=d][n=q], n=l15, k=quad*8+j.
    bf16x8 qf[4][2];
    #pragma unroll
    for (int i = 0; i < 4; i++)
        #pragma unroll
        for (int c = 0; c < 2; c++)
            #pragma unroll
            for (int j = 0; j < 8; j++)
                qf[i][c][j] = (short)Qtb[(size_t)(c * 32 + quad * 8 + j) * SEQ + q0 + i * 16 + l15];

    f32x4 oacc[4][4];                  // [q-frag][d-frag], C: col=q, row=d
    f32x4 oextra[4];                   // ones.P^T -> every row = sum(p) for q=l15
    #pragma unroll
    for (int i = 0; i < 4; i++) {
        oextra[i] = fzero;
        #pragma unroll
        for (int f = 0; f < 4; f++) oacc[i][f] = fzero;
    }

    // stage K/V tile kt into LDS buffer bsel (wave-uniform base + lane*16 dest)
    auto stage = [&](int kt, int bsel) {
        #pragma unroll
        for (int r = 0; r < 2; r++) {
            int g = r * 256 + t, row = g >> 3, cw = g & 7;
            int swz = (cw ^ (row & 7)) * 8;
            gld_lds16(Kb + (size_t)kt * 64 * HD + row * HD + swz, &Kl[bsel][g * 8]);
            gld_lds16(Vb + (size_t)row * SEQ + kt * 64 + swz, &Vl[bsel][g * 8]);
        }
    };

    // prologue
    stage(0, 0);
    asm volatile("s_waitcnt vmcnt(0) lgkmcnt(0)" ::: "memory");
    __builtin_amdgcn_s_barrier();
    __builtin_amdgcn_sched_barrier(0);

    int cur = 0;
    for (int kt = 0; kt < 32; ++kt) {
        if (kt < 31) stage(kt + 1, cur ^ 1);   // prefetch: stays in flight across compute

        const u16* kbuf = &Kl[cur][0];
        const u16* vbuf = &Vl[cur][0];
        bf16x8 ak[2][4], av[2][4];
        #pragma unroll
        for (int f = 0; f < 4; f++) {
            ak[0][f] = *(const bf16x8*)(kbuf + kf0 + f * 1024);
            ak[1][f] = *(const bf16x8*)(kbuf + kf1 + f * 1024);
            av[0][f] = *(const bf16x8*)(vbuf + kf0 + f * 1024);
            av[1][f] = *(const bf16x8*)(vbuf + kf1 + f * 1024);
        }

        #pragma unroll
        for (int i = 0; i < 4; i++) {
            const int par = (i & 1) * 1152;    // i-parity P sub-buffer (elems)
            f32x4 sf[4];
            #pragma unroll
            for (int f = 0; f < 4; f++) sf[f] = fzero;
            __builtin_amdgcn_s_setprio(1);
            #pragma unroll
            for (int c = 0; c < 2; c++)
                #pragma unroll
                for (int f = 0; f < 4; f++)
                    sf[f] = __builtin_amdgcn_mfma_f32_16x16x32_bf16(ak[c][f], qf[i][c], sf[f], 0, 0, 0);
            __builtin_amdgcn_s_setprio(0);

            #pragma unroll
            for (int f = 0; f < 4; f++) {
                float p0 = exp2fast(sf[f][0]);
                float p1 = exp2fast(sf[f][1]);
                float p2 = exp2fast(sf[f][2]);
                float p3 = exp2fast(sf[f][3]);
                uint2 pp = { pkbf(p0, p1), pkbf(p2, p3) };
                *(uint2*)(pww + par + f * 16) = pp;
            }
            bf16x8 bp0 = *(const bf16x8*)(pwr + par);
            bf16x8 bp1 = *(const bf16x8*)(pwr + par + 32);

            __builtin_amdgcn_s_setprio(1);
            #pragma unroll
            for (int f = 0; f < 4; f++) {
                oacc[i][f] = __builtin_amdgcn_mfma_f32_16x16x32_bf16(av[0][f], bp0, oacc[i][f], 0, 0, 0);
                oacc[i][f] = __builtin_amdgcn_mfma_f32_16x16x32_bf16(av[1][f], bp1, oacc[i][f], 0, 0, 0);
            }
            oextra[i] = __builtin_amdgcn_mfma_f32_16x16x32_bf16(ones, bp0, oextra[i], 0, 0, 0);
            oextra[i] = __builtin_amdgcn_mfma_f32_16x16x32_bf16(ones, bp1, oextra[i], 0, 0, 0);
            __builtin_amdgcn_s_setprio(0);
        }

        if (kt < 31) {
            // drain prefetch (latency hidden under the ~5k-cycle body), then
            // one raw barrier: buffer cur^1 is ready, buffer cur reusable.
            asm volatile("s_waitcnt vmcnt(0) lgkmcnt(0)" ::: "memory");
            __builtin_amdgcn_s_barrier();
            __builtin_amdgcn_sched_barrier(0);
        }
        cur ^= 1;
    }

    // epilogue: O^T C-layout -> Oc[b][s][h][d]; d contiguous over regs
    #pragma unroll
    for (int i = 0; i < 4; i++) {
        float inv = 1.0f / oextra[i][0];
        int s = q0 + i * 16 + l15;
        size_t base = ((size_t)(b * SEQ + s) * NH + h) * HD;
        #pragma unroll
        for (int f = 0; f < 4; f++) {
            uint2 o = { pkbf(oacc[i][f][0] * inv, oacc[i][f][1] * inv),
                        pkbf(oacc[i][f][2] * inv, oacc[i][f][3] * inv) };
            *(uint2*)&Oc[base + f * 16 + quad * 4] = o;
        }
    }
}

// ---------------------------------------------------------------------------
// Kernel 4: output projection.  out[8192,1024] = Oc @ WoT^T + bo  (fp32 out)
// ---------------------------------------------------------------------------
__global__ __launch_bounds__(256) void gemm_out(
    const u16* __restrict__ A, const u16* __restrict__ WT,
    const float* __restrict__ bo, float* __restrict__ out)
{
    __shared__ u16 Al[128 * 32];
    __shared__ u16 Bl[128 * 32];
    const int t = threadIdx.x, lane = t & 63, w = t >> 6;
    const int quad = lane >> 4, l15 = lane & 15;
    const int wr = w >> 1, wc = w & 1;
    const int m0 = blockIdx.x * 128, n0 = blockIdx.y * 128;
    const f32x4 fzero = {0.f, 0.f, 0.f, 0.f};

    f32x4 acc[4][4];
    #pragma unroll
    for (int i = 0; i < 4; i++)
        #pragma unroll
        for (int j = 0; j < 4; j++) acc[i][j] = fzero;

    for (int kt = 0; kt < 32; ++kt) {
        #pragma unroll
        for (int r = 0; r < 2; r++) {
            int g = r * 256 + t; int row = g >> 2, cw = g & 3;
            int sc = (cw ^ ((row >> 1) & 3)) * 8;
            gld_lds16(A  + (size_t)(m0 + row) * EMB + kt * 32 + sc, &Al[g * 8]);
            gld_lds16(WT + (size_t)(n0 + row) * EMB + kt * 32 + sc, &Bl[g * 8]);
        }
        __syncthreads();
        bf16x8 af[4], bfr[4];
        #pragma unroll
        for (int i = 0; i < 4; i++) {
            int rowA = wr * 64 + i * 16 + l15;
            af[i] = *(const bf16x8*)&Al[rowA * 32 + ((quad ^ ((rowA >> 1) & 3)) * 8)];
        }
        #pragma unroll
        for (int j = 0; j < 4; j++) {
            int rowB = wc * 64 + j * 16 + l15;
            bfr[j] = *(const bf16x8*)&Bl[rowB * 32 + ((quad ^ ((rowB >> 1) & 3)) * 8)];
        }
        #pragma unroll
        for (int i = 0; i < 4; i++)
            #pragma unroll
            for (int j = 0; j < 4; j++)
                acc[i][j] = __builtin_amdgcn_mfma_f32_16x16x32_bf16(af[i], bfr[j], acc[i][j], 0, 0, 0);
        __syncthreads();
    }

    #pragma unroll
    for (int j = 0; j < 4; j++) {
        int n = n0 + wc * 64 + j * 16 + l15;
        float bvl = bo[n];
        #pragma unroll
        for (int i = 0; i < 4; i++) {
            int m = m0 + wr * 64 + i * 16 + quad * 4;
            #pragma unroll
            for (int r = 0; r < 4; r++)
                out[(size_t)(m + r) * EMB + n] = acc[i][j][r] + bvl;
        }
    }
}

// ---------------------------------------------------------------------------
extern "C" void kernel_launch(void* const* d_in, const int* in_sizes, int n_in,
                              void* d_out, int out_size, void* d_ws, size_t ws_size,
                              hipStream_t stream)
{
    (void)in_sizes; (void)n_in; (void)out_size; (void)ws_size;
    const float* x  = (const float*)d_in[0];
    const float* Wq = (const float*)d_in[1];
    const float* bq = (const float*)d_in[2];
    const float* Wk = (const float*)d_in[3];
    const float* bk = (const float*)d_in[4];
    const float* Wv = (const float*)d_in[5];
    const float* bv = (const float*)d_in[6];
    const float* Wo = (const float*)d_in[7];
    const float* bo = (const float*)d_in[8];
    u16* ws = (u16*)d_ws;
    u16* Xb = (u16*)d_out;   // bf16 copy of x lives in d_out until gemm_out runs

    convert_x<<<dim3(8192), 256, 0, stream>>>(x, Xb);
    transpose_w<<<dim3(16, 16, 4), 256, 0, stream>>>(Wq, Wk, Wv, Wo, ws);
    gemm_qkv<<<dim3(64, 24), 256, 0, stream>>>(Xb, ws + OFF_WT, bq, bk, bv,
                                               ws + OFF_Q, ws + OFF_K, ws + OFF_VT);
    flash_attn<<<dim3(8, 64), 256, 0, stream>>>(ws + OFF_Q, ws + OFF_K,
                                                ws + OFF_VT, ws + OFF_OC);
    gemm_out<<<dim3(64, 8), 256, 0, stream>>>(ws + OFF_OC, ws + OFF_WOT, bo, (float*)d_out);
}

// Round 2
// 293.433 us; speedup vs baseline: 1.0085x; 1.0085x over previous
//
#include <hip/hip_runtime.h>
#include <hip/hip_bf16.h>

typedef unsigned short u16;
typedef __attribute__((ext_vector_type(8))) short bf16x8;
typedef __attribute__((ext_vector_type(4))) float f32x4;
typedef __attribute__((ext_vector_type(4))) unsigned int u32x4;

#define EMB 1024
#define SEQ 2048
#define NH 16
#define HD 64

// ws element offsets (bf16 elems)
#define OFF_WT   0u          // [3072][1024]  WqT|WkT|WvT (bf16)
#define OFF_WOT  3145728u    // [1024][1024]  WoT (bf16)
#define OFF_Q    4194304u    // [64][64][2048]  (bh, d, s)  Q^T, pre-scaled by 0.125*log2e
#define OFF_K    12582912u   // [64][2048][64]  (bh, s, d)
#define OFF_VT   20971520u   // [64][64][2048]  (bh, d, s)  V transposed
#define OFF_OC   29360128u   // [8192][1024]   attn output, concat layout
// Xb (x in bf16) lives in d_out until gemm_out overwrites it (stream-ordered).

#define QSCALE 0.1803368801111f   // 0.125 * log2(e)

__device__ __forceinline__ u16 f2bf(float f) {
    unsigned int x; __builtin_memcpy(&x, &f, 4);
    unsigned int r = x + 0x7fffu + ((x >> 16) & 1u);   // RNE
    return (u16)(r >> 16);
}

#if defined(__has_builtin) && __has_builtin(__builtin_amdgcn_cvt_pk_bf16_f32)
typedef __attribute__((ext_vector_type(2))) __bf16 bfv2;
__device__ __forceinline__ unsigned int pkbf(float a, float b) {
    bfv2 v = __builtin_amdgcn_cvt_pk_bf16_f32(a, b);   // elem0 = a (low half)
    unsigned int u; __builtin_memcpy(&u, &v, 4); return u;
}
#else
__device__ __forceinline__ unsigned int pkbf(float a, float b) {
    return (unsigned)f2bf(a) | ((unsigned)f2bf(b) << 16);
}
#endif

// bare v_exp_f32 (no overflow/denorm guards; scores are |x| < ~30 << 126)
#if defined(__has_builtin) && __has_builtin(__builtin_amdgcn_exp2f)
__device__ __forceinline__ float exp2fast(float x) { return __builtin_amdgcn_exp2f(x); }
#else
__device__ __forceinline__ float exp2fast(float x) { return __builtin_exp2f(x); }
#endif

__device__ __forceinline__ void gld_lds16(const void* gsrc, void* ldst) {
    void* g = const_cast<void*>(gsrc);
    __builtin_amdgcn_global_load_lds((__attribute__((address_space(1))) void*)g,
                                     (__attribute__((address_space(3))) void*)ldst,
                                     16, 0, 0);
}

// ---------------------------------------------------------------------------
// Kernel 0: convert x (fp32) -> Xb (bf16), 4 elems/thread.
// ---------------------------------------------------------------------------
__global__ __launch_bounds__(256) void convert_x(
    const float* __restrict__ x, u16* __restrict__ xb)
{
    int i = (blockIdx.x * 256 + threadIdx.x) * 4;
    float4 v = *(const float4*)&x[i];
    uint2 o = { pkbf(v.x, v.y), pkbf(v.z, v.w) };
    *(uint2*)&xb[i] = o;
}

// ---------------------------------------------------------------------------
// Kernel 1: transpose the four 1024x1024 fp32 weights into ws as bf16.
// ---------------------------------------------------------------------------
__global__ __launch_bounds__(256) void transpose_w(
    const float* __restrict__ W0, const float* __restrict__ W1,
    const float* __restrict__ W2, const float* __restrict__ W3,
    u16* __restrict__ ws)
{
    __shared__ u16 tile[64 * 65];
    const float* src = blockIdx.z == 0 ? W0 : blockIdx.z == 1 ? W1 : blockIdx.z == 2 ? W2 : W3;
    u16* dst = ws + (blockIdx.z < 3 ? (unsigned)blockIdx.z * 1048576u : OFF_WOT);
    const int k0 = blockIdx.x * 64, n0 = blockIdx.y * 64;
    const int t = threadIdx.x;
    #pragma unroll
    for (int i = 0; i < 16; i++) {
        int idx = i * 256 + t; int r = idx >> 6, c = idx & 63;
        tile[c * 65 + r] = f2bf(src[(k0 + r) * EMB + n0 + c]);
    }
    __syncthreads();
    #pragma unroll
    for (int i = 0; i < 16; i++) {
        int idx = i * 256 + t; int r = idx >> 6, c = idx & 63;
        dst[(n0 + r) * EMB + k0 + c] = tile[r * 65 + c];
    }
}

// ---------------------------------------------------------------------------
// Kernel 2: fused QKV projection.  C[8192,3072] = Xb[8192,1024] @ WT^T (+bias)
// Q segment: scaled by QSCALE and stored TRANSPOSED [bh][d][s] (packed u2).
// V segment: stored transposed [bh][d][s].  K: [bh][s][d] (flash A-frags).
// ---------------------------------------------------------------------------
__global__ __launch_bounds__(256) void gemm_qkv(
    const u16* __restrict__ X, const u16* __restrict__ WT,
    const float* __restrict__ bq, const float* __restrict__ bk, const float* __restrict__ bv,
    u16* __restrict__ Qt, u16* __restrict__ Ko, u16* __restrict__ Vt)
{
    __shared__ u16 Al[128 * 32];
    __shared__ u16 Bl[128 * 32];
    const int t = threadIdx.x, lane = t & 63, w = t >> 6;
    const int quad = lane >> 4, l15 = lane & 15;
    const int wr = w >> 1, wc = w & 1;
    const int m0 = blockIdx.x * 128, n0 = blockIdx.y * 128;
    const f32x4 fzero = {0.f, 0.f, 0.f, 0.f};

    f32x4 acc[4][4];
    #pragma unroll
    for (int i = 0; i < 4; i++)
        #pragma unroll
        for (int j = 0; j < 4; j++) acc[i][j] = fzero;

    for (int kt = 0; kt < 32; ++kt) {
        #pragma unroll
        for (int r = 0; r < 2; r++) {
            int g = r * 256 + t; int row = g >> 2, cw = g & 3;
            int sc = (cw ^ ((row >> 1) & 3)) * 8;
            gld_lds16(X  + (size_t)(m0 + row) * EMB + kt * 32 + sc, &Al[g * 8]);
            gld_lds16(WT + (size_t)(n0 + row) * EMB + kt * 32 + sc, &Bl[g * 8]);
        }
        __syncthreads();
        bf16x8 af[4], bfr[4];
        #pragma unroll
        for (int i = 0; i < 4; i++) {
            int rowA = wr * 64 + i * 16 + l15;
            af[i] = *(const bf16x8*)&Al[rowA * 32 + ((quad ^ ((rowA >> 1) & 3)) * 8)];
        }
        #pragma unroll
        for (int j = 0; j < 4; j++) {
            int rowB = wc * 64 + j * 16 + l15;
            bfr[j] = *(const bf16x8*)&Bl[rowB * 32 + ((quad ^ ((rowB >> 1) & 3)) * 8)];
        }
        #pragma unroll
        for (int i = 0; i < 4; i++)
            #pragma unroll
            for (int j = 0; j < 4; j++)
                acc[i][j] = __builtin_amdgcn_mfma_f32_16x16x32_bf16(af[i], bfr[j], acc[i][j], 0, 0, 0);
        __syncthreads();
    }

    const int seg = n0 >> 10;
    const float* bias = seg == 0 ? bq : (seg == 1 ? bk : bv);
    #pragma unroll
    for (int j = 0; j < 4; j++) {
        int n = n0 + wc * 64 + j * 16 + l15;
        int nn = n & 1023;
        float bvl = bias[nn];
        int h = nn >> 6, d = nn & 63;
        #pragma unroll
        for (int i = 0; i < 4; i++) {
            int m = m0 + wr * 64 + i * 16 + quad * 4;
            int b = m >> 11, s = m & 2047;
            if (seg == 0) {          // Q^T, scaled: [bh][d][s], s packed over regs
                uint2 pp = { pkbf((acc[i][j][0] + bvl) * QSCALE, (acc[i][j][1] + bvl) * QSCALE),
                             pkbf((acc[i][j][2] + bvl) * QSCALE, (acc[i][j][3] + bvl) * QSCALE) };
                *(uint2*)&Qt[(size_t)((b * NH + h) * HD + d) * SEQ + s] = pp;
            } else if (seg == 2) {   // V^T: [bh][d][s]
                uint2 pp = { pkbf(acc[i][j][0] + bvl, acc[i][j][1] + bvl),
                             pkbf(acc[i][j][2] + bvl, acc[i][j][3] + bvl) };
                *(uint2*)&Vt[(size_t)((b * NH + h) * HD + d) * SEQ + s] = pp;
            } else {                 // K: [bh][s][d]
                size_t base = (size_t)((b * NH + h) * SEQ + s) * HD + d;
                #pragma unroll
                for (int r = 0; r < 4; r++) Ko[base + (size_t)r * HD] = f2bf(acc[i][j][r] + bvl);
            }
        }
    }
}

// ---------------------------------------------------------------------------
// Kernel 3: flash attention.
// Round-2:
//  - XCD-aware bh grouping: lin%8 = XCD (grid 512, x-fastest); XCD k owns
//    bh in [8k, 8k+8) so its K/V working set = 4MB = its L2.  The 8 q-blocks
//    of one bh are co-resident on ONE XCD -> K/V tiles re-read from L2, not
//    L3/HBM (was: same-bh blocks spread over all 8 XCDs, FETCH ~= 4x K/V).
//  - T12: P redistribution fully in-register via v_permlane32/16_swap_b32;
//    P LDS buffer deleted (conflicts were 8-way on its reads; 6.29M cycles).
//    LDS 50KB -> 32KB.
// ---------------------------------------------------------------------------
__global__ __launch_bounds__(256, 2) void flash_attn(
    const u16* __restrict__ Q, const u16* __restrict__ K,
    const u16* __restrict__ VT, u16* __restrict__ Oc)
{
    __shared__ u16 Kl[2][64 * 64];     // [buf][key][d], chunk-swizzled
    __shared__ u16 Vl[2][64 * 64];     // [buf][d][key], chunk-swizzled
    const int t = threadIdx.x, lane = t & 63, w = t >> 6;
    const int quad = lane >> 4, l15 = lane & 15;
    const int a7 = l15 & 7;

    // XCD-aware remap: xcd = lin&7 owns bh in [xcd*8, xcd*8+8)
    const int lin = blockIdx.x;
    const int xcd = lin & 7, slot = lin >> 3;
    const int bh = xcd * 8 + (slot >> 3);
    const int qx = slot & 7;
    const int b = bh >> 4, h = bh & 15;
    const int q0 = qx * 256 + w * 64;

    const u16* Qtb = Q + (size_t)bh * HD * SEQ;    // Q^T [d][s]
    const u16* Kb  = K + (size_t)bh * SEQ * HD;
    const u16* Vb  = VT + (size_t)bh * HD * SEQ;
    const f32x4 fzero = {0.f, 0.f, 0.f, 0.f};

    // fragment element-offsets within one K/V buffer (f-invariant: (f*16+l15)&7 == l15&7)
    const int kf0 = l15 * 64 + ((quad ^ a7) * 8);
    const int kf1 = l15 * 64 + (((4 + quad) ^ a7) * 8);

    // constant all-ones A fragment (bf16 1.0 = 0x3F80)
    bf16x8 ones;
    #pragma unroll
    for (int j = 0; j < 8; j++) ones[j] = (short)0x3F80;

    // Q as B-operand fragments (persistent): B[k=d][n=q], n=l15, k=quad*8+j.
    bf16x8 qf[4][2];
    #pragma unroll
    for (int i = 0; i < 4; i++)
        #pragma unroll
        for (int c = 0; c < 2; c++)
            #pragma unroll
            for (int j = 0; j < 8; j++)
                qf[i][c][j] = (short)Qtb[(size_t)(c * 32 + quad * 8 + j) * SEQ + q0 + i * 16 + l15];

    f32x4 oacc[4][4];                  // [q-frag][d-frag], C: col=q, row=d
    f32x4 oextra[4];                   // ones.P^T -> every row = sum(p) for q=l15
    #pragma unroll
    for (int i = 0; i < 4; i++) {
        oextra[i] = fzero;
        #pragma unroll
        for (int f = 0; f < 4; f++) oacc[i][f] = fzero;
    }

    // stage K/V tile kt into LDS buffer bsel (wave-uniform base + lane*16 dest)
    auto stage = [&](int kt, int bsel) {
        #pragma unroll
        for (int r = 0; r < 2; r++) {
            int g = r * 256 + t, row = g >> 3, cw = g & 7;
            int swz = (cw ^ (row & 7)) * 8;
            gld_lds16(Kb + (size_t)kt * 64 * HD + row * HD + swz, &Kl[bsel][g * 8]);
            gld_lds16(Vb + (size_t)row * SEQ + kt * 64 + swz, &Vl[bsel][g * 8]);
        }
    };

    // prologue
    stage(0, 0);
    asm volatile("s_waitcnt vmcnt(0) lgkmcnt(0)" ::: "memory");
    __builtin_amdgcn_s_barrier();
    __builtin_amdgcn_sched_barrier(0);

    int cur = 0;
    for (int kt = 0; kt < 32; ++kt) {
        if (kt < 31) stage(kt + 1, cur ^ 1);   // prefetch: stays in flight across compute

        const u16* kbuf = &Kl[cur][0];
        const u16* vbuf = &Vl[cur][0];
        bf16x8 ak[2][4], av[2][4];
        #pragma unroll
        for (int f = 0; f < 4; f++) {
            ak[0][f] = *(const bf16x8*)(kbuf + kf0 + f * 1024);
            ak[1][f] = *(const bf16x8*)(kbuf + kf1 + f * 1024);
            av[0][f] = *(const bf16x8*)(vbuf + kf0 + f * 1024);
            av[1][f] = *(const bf16x8*)(vbuf + kf1 + f * 1024);
        }

        #pragma unroll
        for (int i = 0; i < 4; i++) {
            // ---- QK^T: C[m=key][n=q], lane holds keys f*16+quad*4+r, q=l15 ----
            f32x4 sf[4];
            #pragma unroll
            for (int f = 0; f < 4; f++) sf[f] = fzero;
            __builtin_amdgcn_s_setprio(1);
            #pragma unroll
            for (int c = 0; c < 2; c++)
                #pragma unroll
                for (int f = 0; f < 4; f++)
                    sf[f] = __builtin_amdgcn_mfma_f32_16x16x32_bf16(ak[c][f], qf[i][c], sf[f], 0, 0, 0);
            __builtin_amdgcn_s_setprio(0);

            // ---- exp2 -> bf16 pairs: pa[f][h] = keys f*16+quad*4+{2h,2h+1} ----
            unsigned int pa[4][2];
            #pragma unroll
            for (int f = 0; f < 4; f++) {
                pa[f][0] = pkbf(exp2fast(sf[f][0]), exp2fast(sf[f][1]));
                pa[f][1] = pkbf(exp2fast(sf[f][2]), exp2fast(sf[f][3]));
            }

            // ---- T12: in-register redistribution to PV B-fragments.
            // Target bp word w (keys quad*8+2w+{0,1}): f=quad>>1, q_src=(quad&1)*2+(w>>1), h=w&1.
            // permlane32_swap(X,Y): X'=[X0,X1,Y0,Y1], Y'=[X2,X3,Y2,Y3]  (quads)
            // permlane16_swap(A,B): A'=[A0,B0,A2,B2], B'=[A1,B1,A3,B3]
            // => Z=[X0,X2,Y0,Y2] (word w=h), W=[X1,X3,Y1,Y3] (word w=h+2)
            unsigned int z0 = pa[0][0], w0 = pa[1][0];
            asm("v_permlane32_swap_b32 %0, %1" : "+v"(z0), "+v"(w0));
            asm("v_permlane16_swap_b32 %0, %1" : "+v"(z0), "+v"(w0));
            unsigned int z1 = pa[0][1], w1 = pa[1][1];
            asm("v_permlane32_swap_b32 %0, %1" : "+v"(z1), "+v"(w1));
            asm("v_permlane16_swap_b32 %0, %1" : "+v"(z1), "+v"(w1));
            unsigned int z2 = pa[2][0], w2 = pa[3][0];
            asm("v_permlane32_swap_b32 %0, %1" : "+v"(z2), "+v"(w2));
            asm("v_permlane16_swap_b32 %0, %1" : "+v"(z2), "+v"(w2));
            unsigned int z3 = pa[2][1], w3 = pa[3][1];
            asm("v_permlane32_swap_b32 %0, %1" : "+v"(z3), "+v"(w3));
            asm("v_permlane16_swap_b32 %0, %1" : "+v"(z3), "+v"(w3));

            bf16x8 bp0, bp1;
            { u32x4 u = {z0, z1, w0, w1}; __builtin_memcpy(&bp0, &u, 16); }
            { u32x4 u = {z2, z3, w2, w3}; __builtin_memcpy(&bp1, &u, 16); }

            // ---- PV + ones row-sum ----
            __builtin_amdgcn_s_setprio(1);
            #pragma unroll
            for (int f = 0; f < 4; f++) {
                oacc[i][f] = __builtin_amdgcn_mfma_f32_16x16x32_bf16(av[0][f], bp0, oacc[i][f], 0, 0, 0);
                oacc[i][f] = __builtin_amdgcn_mfma_f32_16x16x32_bf16(av[1][f], bp1, oacc[i][f], 0, 0, 0);
            }
            oextra[i] = __builtin_amdgcn_mfma_f32_16x16x32_bf16(ones, bp0, oextra[i], 0, 0, 0);
            oextra[i] = __builtin_amdgcn_mfma_f32_16x16x32_bf16(ones, bp1, oextra[i], 0, 0, 0);
            __builtin_amdgcn_s_setprio(0);
        }

        if (kt < 31) {
            // drain prefetch (latency hidden under compute), then one raw
            // barrier: buffer cur^1 is ready, buffer cur reusable.
            asm volatile("s_waitcnt vmcnt(0) lgkmcnt(0)" ::: "memory");
            __builtin_amdgcn_s_barrier();
            __builtin_amdgcn_sched_barrier(0);
        }
        cur ^= 1;
    }

    // epilogue: O^T C-layout -> Oc[b][s][h][d]; d contiguous over regs
    #pragma unroll
    for (int i = 0; i < 4; i++) {
        float inv = 1.0f / oextra[i][0];
        int s = q0 + i * 16 + l15;
        size_t base = ((size_t)(b * SEQ + s) * NH + h) * HD;
        #pragma unroll
        for (int f = 0; f < 4; f++) {
            uint2 o = { pkbf(oacc[i][f][0] * inv, oacc[i][f][1] * inv),
                        pkbf(oacc[i][f][2] * inv, oacc[i][f][3] * inv) };
            *(uint2*)&Oc[base + f * 16 + quad * 4] = o;
        }
    }
}

// ---------------------------------------------------------------------------
// Kernel 4: output projection.  out[8192,1024] = Oc @ WoT^T + bo  (fp32 out)
// ---------------------------------------------------------------------------
__global__ __launch_bounds__(256) void gemm_out(
    const u16* __restrict__ A, const u16* __restrict__ WT,
    const float* __restrict__ bo, float* __restrict__ out)
{
    __shared__ u16 Al[128 * 32];
    __shared__ u16 Bl[128 * 32];
    const int t = threadIdx.x, lane = t & 63, w = t >> 6;
    const int quad = lane >> 4, l15 = lane & 15;
    const int wr = w >> 1, wc = w & 1;
    const int m0 = blockIdx.x * 128, n0 = blockIdx.y * 128;
    const f32x4 fzero = {0.f, 0.f, 0.f, 0.f};

    f32x4 acc[4][4];
    #pragma unroll
    for (int i = 0; i < 4; i++)
        #pragma unroll
        for (int j = 0; j < 4; j++) acc[i][j] = fzero;

    for (int kt = 0; kt < 32; ++kt) {
        #pragma unroll
        for (int r = 0; r < 2; r++) {
            int g = r * 256 + t; int row = g >> 2, cw = g & 3;
            int sc = (cw ^ ((row >> 1) & 3)) * 8;
            gld_lds16(A  + (size_t)(m0 + row) * EMB + kt * 32 + sc, &Al[g * 8]);
            gld_lds16(WT + (size_t)(n0 + row) * EMB + kt * 32 + sc, &Bl[g * 8]);
        }
        __syncthreads();
        bf16x8 af[4], bfr[4];
        #pragma unroll
        for (int i = 0; i < 4; i++) {
            int rowA = wr * 64 + i * 16 + l15;
            af[i] = *(const bf16x8*)&Al[rowA * 32 + ((quad ^ ((rowA >> 1) & 3)) * 8)];
        }
        #pragma unroll
        for (int j = 0; j < 4; j++) {
            int rowB = wc * 64 + j * 16 + l15;
            bfr[j] = *(const bf16x8*)&Bl[rowB * 32 + ((quad ^ ((rowB >> 1) & 3)) * 8)];
        }
        #pragma unroll
        for (int i = 0; i < 4; i++)
            #pragma unroll
            for (int j = 0; j < 4; j++)
                acc[i][j] = __builtin_amdgcn_mfma_f32_16x16x32_bf16(af[i], bfr[j], acc[i][j], 0, 0, 0);
        __syncthreads();
    }

    #pragma unroll
    for (int j = 0; j < 4; j++) {
        int n = n0 + wc * 64 + j * 16 + l15;
        float bvl = bo[n];
        #pragma unroll
        for (int i = 0; i < 4; i++) {
            int m = m0 + wr * 64 + i * 16 + quad * 4;
            #pragma unroll
            for (int r = 0; r < 4; r++)
                out[(size_t)(m + r) * EMB + n] = acc[i][j][r] + bvl;
        }
    }
}

// ---------------------------------------------------------------------------
extern "C" void kernel_launch(void* const* d_in, const int* in_sizes, int n_in,
                              void* d_out, int out_size, void* d_ws, size_t ws_size,
                              hipStream_t stream)
{
    (void)in_sizes; (void)n_in; (void)out_size; (void)ws_size;
    const float* x  = (const float*)d_in[0];
    const float* Wq = (const float*)d_in[1];
    const float* bq = (const float*)d_in[2];
    const float* Wk = (const float*)d_in[3];
    const float* bk = (const float*)d_in[4];
    const float* Wv = (const float*)d_in[5];
    const float* bv = (const float*)d_in[6];
    const float* Wo = (const float*)d_in[7];
    const float* bo = (const float*)d_in[8];
    u16* ws = (u16*)d_ws;
    u16* Xb = (u16*)d_out;   // bf16 copy of x lives in d_out until gemm_out runs

    convert_x<<<dim3(8192), 256, 0, stream>>>(x, Xb);
    transpose_w<<<dim3(16, 16, 4), 256, 0, stream>>>(Wq, Wk, Wv, Wo, ws);
    gemm_qkv<<<dim3(64, 24), 256, 0, stream>>>(Xb, ws + OFF_WT, bq, bk, bv,
                                               ws + OFF_Q, ws + OFF_K, ws + OFF_VT);
    flash_attn<<<dim3(512), 256, 0, stream>>>(ws + OFF_Q, ws + OFF_K,
                                              ws + OFF_VT, ws + OFF_OC);
    gemm_out<<<dim3(64, 8), 256, 0, stream>>>(ws + OFF_OC, ws + OFF_WOT, bo, (float*)d_out);
}

// Round 3
// 279.110 us; speedup vs baseline: 1.0602x; 1.0513x over previous
//
#include <hip/hip_runtime.h>
#include <hip/hip_bf16.h>

typedef unsigned short u16;
typedef __attribute__((ext_vector_type(8))) short bf16x8;
typedef __attribute__((ext_vector_type(4))) float f32x4;
typedef __attribute__((ext_vector_type(4))) unsigned int u32x4;

#define EMB 1024
#define SEQ 2048
#define NH 16
#define HD 64

// ws element offsets (bf16 elems)
#define OFF_WT   0u          // [3072][1024]  WqT|WkT|WvT (bf16)
#define OFF_WOT  3145728u    // [1024][1024]  WoT (bf16)
#define OFF_Q    4194304u    // [64][64][2048]  (bh, d, s)  Q^T, pre-scaled by 0.125*log2e
#define OFF_K    12582912u   // [64][2048][64]  (bh, s, d)
#define OFF_VT   20971520u   // [64][64][2048]  (bh, d, s)  V transposed
#define OFF_OC   29360128u   // [8192][1024]   attn output, concat layout
// Xb (x in bf16) lives in d_out until gemm_out overwrites it (stream-ordered).

#define QSCALE 0.1803368801111f   // 0.125 * log2(e)

__device__ __forceinline__ u16 f2bf(float f) {
    unsigned int x; __builtin_memcpy(&x, &f, 4);
    unsigned int r = x + 0x7fffu + ((x >> 16) & 1u);   // RNE
    return (u16)(r >> 16);
}

#if defined(__has_builtin) && __has_builtin(__builtin_amdgcn_cvt_pk_bf16_f32)
typedef __attribute__((ext_vector_type(2))) __bf16 bfv2;
__device__ __forceinline__ unsigned int pkbf(float a, float b) {
    bfv2 v = __builtin_amdgcn_cvt_pk_bf16_f32(a, b);   // elem0 = a (low half)
    unsigned int u; __builtin_memcpy(&u, &v, 4); return u;
}
#else
__device__ __forceinline__ unsigned int pkbf(float a, float b) {
    return (unsigned)f2bf(a) | ((unsigned)f2bf(b) << 16);
}
#endif

// bare v_exp_f32 (no overflow/denorm guards; scores are |x| < ~30 << 126)
#if defined(__has_builtin) && __has_builtin(__builtin_amdgcn_exp2f)
__device__ __forceinline__ float exp2fast(float x) { return __builtin_amdgcn_exp2f(x); }
#else
__device__ __forceinline__ float exp2fast(float x) { return __builtin_exp2f(x); }
#endif

__device__ __forceinline__ void gld_lds16(const void* gsrc, void* ldst) {
    void* g = const_cast<void*>(gsrc);
    __builtin_amdgcn_global_load_lds((__attribute__((address_space(1))) void*)g,
                                     (__attribute__((address_space(3))) void*)ldst,
                                     16, 0, 0);
}

// ---------------------------------------------------------------------------
// Kernel 0: convert x (fp32) -> Xb (bf16), 4 elems/thread.
// ---------------------------------------------------------------------------
__global__ __launch_bounds__(256) void convert_x(
    const float* __restrict__ x, u16* __restrict__ xb)
{
    int i = (blockIdx.x * 256 + threadIdx.x) * 4;
    float4 v = *(const float4*)&x[i];
    uint2 o = { pkbf(v.x, v.y), pkbf(v.z, v.w) };
    *(uint2*)&xb[i] = o;
}

// ---------------------------------------------------------------------------
// Kernel 1: transpose the four 1024x1024 fp32 weights into ws as bf16.
// ---------------------------------------------------------------------------
__global__ __launch_bounds__(256) void transpose_w(
    const float* __restrict__ W0, const float* __restrict__ W1,
    const float* __restrict__ W2, const float* __restrict__ W3,
    u16* __restrict__ ws)
{
    __shared__ u16 tile[64 * 65];
    const float* src = blockIdx.z == 0 ? W0 : blockIdx.z == 1 ? W1 : blockIdx.z == 2 ? W2 : W3;
    u16* dst = ws + (blockIdx.z < 3 ? (unsigned)blockIdx.z * 1048576u : OFF_WOT);
    const int k0 = blockIdx.x * 64, n0 = blockIdx.y * 64;
    const int t = threadIdx.x;
    #pragma unroll
    for (int i = 0; i < 16; i++) {
        int idx = i * 256 + t; int r = idx >> 6, c = idx & 63;
        tile[c * 65 + r] = f2bf(src[(k0 + r) * EMB + n0 + c]);
    }
    __syncthreads();
    #pragma unroll
    for (int i = 0; i < 16; i++) {
        int idx = i * 256 + t; int r = idx >> 6, c = idx & 63;
        dst[(n0 + r) * EMB + k0 + c] = tile[r * 65 + c];
    }
}

// ---------------------------------------------------------------------------
// Kernel 2: fused QKV projection.  C[8192,3072] = Xb[8192,1024] @ WT^T (+bias)
// Q segment: scaled by QSCALE and stored TRANSPOSED [bh][d][s] (packed u2).
// V segment: stored transposed [bh][d][s].  K: [bh][s][d] (flash A-frags).
// ---------------------------------------------------------------------------
__global__ __launch_bounds__(256) void gemm_qkv(
    const u16* __restrict__ X, const u16* __restrict__ WT,
    const float* __restrict__ bq, const float* __restrict__ bk, const float* __restrict__ bv,
    u16* __restrict__ Qt, u16* __restrict__ Ko, u16* __restrict__ Vt)
{
    __shared__ u16 Al[128 * 32];
    __shared__ u16 Bl[128 * 32];
    const int t = threadIdx.x, lane = t & 63, w = t >> 6;
    const int quad = lane >> 4, l15 = lane & 15;
    const int wr = w >> 1, wc = w & 1;
    const int m0 = blockIdx.x * 128, n0 = blockIdx.y * 128;
    const f32x4 fzero = {0.f, 0.f, 0.f, 0.f};

    f32x4 acc[4][4];
    #pragma unroll
    for (int i = 0; i < 4; i++)
        #pragma unroll
        for (int j = 0; j < 4; j++) acc[i][j] = fzero;

    for (int kt = 0; kt < 32; ++kt) {
        #pragma unroll
        for (int r = 0; r < 2; r++) {
            int g = r * 256 + t; int row = g >> 2, cw = g & 3;
            int sc = (cw ^ ((row >> 1) & 3)) * 8;
            gld_lds16(X  + (size_t)(m0 + row) * EMB + kt * 32 + sc, &Al[g * 8]);
            gld_lds16(WT + (size_t)(n0 + row) * EMB + kt * 32 + sc, &Bl[g * 8]);
        }
        __syncthreads();
        bf16x8 af[4], bfr[4];
        #pragma unroll
        for (int i = 0; i < 4; i++) {
            int rowA = wr * 64 + i * 16 + l15;
            af[i] = *(const bf16x8*)&Al[rowA * 32 + ((quad ^ ((rowA >> 1) & 3)) * 8)];
        }
        #pragma unroll
        for (int j = 0; j < 4; j++) {
            int rowB = wc * 64 + j * 16 + l15;
            bfr[j] = *(const bf16x8*)&Bl[rowB * 32 + ((quad ^ ((rowB >> 1) & 3)) * 8)];
        }
        #pragma unroll
        for (int i = 0; i < 4; i++)
            #pragma unroll
            for (int j = 0; j < 4; j++)
                acc[i][j] = __builtin_amdgcn_mfma_f32_16x16x32_bf16(af[i], bfr[j], acc[i][j], 0, 0, 0);
        __syncthreads();
    }

    const int seg = n0 >> 10;
    const float* bias = seg == 0 ? bq : (seg == 1 ? bk : bv);
    #pragma unroll
    for (int j = 0; j < 4; j++) {
        int n = n0 + wc * 64 + j * 16 + l15;
        int nn = n & 1023;
        float bvl = bias[nn];
        int h = nn >> 6, d = nn & 63;
        #pragma unroll
        for (int i = 0; i < 4; i++) {
            int m = m0 + wr * 64 + i * 16 + quad * 4;
            int b = m >> 11, s = m & 2047;
            if (seg == 0) {          // Q^T, scaled: [bh][d][s], s packed over regs
                uint2 pp = { pkbf((acc[i][j][0] + bvl) * QSCALE, (acc[i][j][1] + bvl) * QSCALE),
                             pkbf((acc[i][j][2] + bvl) * QSCALE, (acc[i][j][3] + bvl) * QSCALE) };
                *(uint2*)&Qt[(size_t)((b * NH + h) * HD + d) * SEQ + s] = pp;
            } else if (seg == 2) {   // V^T: [bh][d][s]
                uint2 pp = { pkbf(acc[i][j][0] + bvl, acc[i][j][1] + bvl),
                             pkbf(acc[i][j][2] + bvl, acc[i][j][3] + bvl) };
                *(uint2*)&Vt[(size_t)((b * NH + h) * HD + d) * SEQ + s] = pp;
            } else {                 // K: [bh][s][d]
                size_t base = (size_t)((b * NH + h) * SEQ + s) * HD + d;
                #pragma unroll
                for (int r = 0; r < 4; r++) Ko[base + (size_t)r * HD] = f2bf(acc[i][j][r] + bvl);
            }
        }
    }
}

// ---------------------------------------------------------------------------
// Kernel 3: flash attention.
// Round-3:
//  - K rows PRE-PERMUTED at stage time (pi(m) = 32*rh + qhat*8 + 2f + rl) so
//    QK's C-layout, after exp2 + cvt_pk, lands DIRECTLY in PV B-fragment word
//    order: all 32 permlanes/wave-kt deleted (values bit-identical; row-sum
//    and V k-indexing are permutation-consistent).
//  - T4 proper: 4-buffer LDS (64KB), 2-deep prefetch, counted vmcnt(16) at
//    top of body; no drain-to-0 in the loop, single pure-sync barrier per kt.
//    Buffer reuse distance kt+2-write vs kt-2-read is 2 barriers apart.
//  - fzero fed as MFMA C-in (no per-i sf re-zeroing movs).
// ---------------------------------------------------------------------------
__global__ __launch_bounds__(256, 2) void flash_attn(
    const u16* __restrict__ Q, const u16* __restrict__ K,
    const u16* __restrict__ VT, u16* __restrict__ Oc)
{
    __shared__ u16 Kl[4][64 * 64];     // [buf][key_lds][d], chunk-swizzled, rows permuted
    __shared__ u16 Vl[4][64 * 64];     // [buf][d][key], chunk-swizzled
    const int t = threadIdx.x, lane = t & 63, w = t >> 6;
    const int quad = lane >> 4, l15 = lane & 15;
    const int a7 = l15 & 7;

    // XCD-aware remap: xcd = lin&7 owns bh in [xcd*8, xcd*8+8)
    const int lin = blockIdx.x;
    const int xcd = lin & 7, slot = lin >> 3;
    const int bh = xcd * 8 + (slot >> 3);
    const int qx = slot & 7;
    const int b = bh >> 4, h = bh & 15;
    const int q0 = qx * 256 + w * 64;

    const u16* Qtb = Q + (size_t)bh * HD * SEQ;    // Q^T [d][s]
    const u16* Kb  = K + (size_t)bh * SEQ * HD;
    const u16* Vb  = VT + (size_t)bh * HD * SEQ;
    const f32x4 fzero = {0.f, 0.f, 0.f, 0.f};

    // fragment element-offsets within one K/V buffer (f-invariant: (f*16+l15)&7 == l15&7)
    const int kf0 = l15 * 64 + ((quad ^ a7) * 8);
    const int kf1 = l15 * 64 + (((4 + quad) ^ a7) * 8);

    // constant all-ones A fragment (bf16 1.0 = 0x3F80)
    bf16x8 ones;
    #pragma unroll
    for (int j = 0; j < 8; j++) ones[j] = (short)0x3F80;

    // Q as B-operand fragments (persistent): B[k=d][n=q], n=l15, k=quad*8+j.
    bf16x8 qf[4][2];
    #pragma unroll
    for (int i = 0; i < 4; i++)
        #pragma unroll
        for (int c = 0; c < 2; c++)
            #pragma unroll
            for (int j = 0; j < 8; j++)
                qf[i][c][j] = (short)Qtb[(size_t)(c * 32 + quad * 8 + j) * SEQ + q0 + i * 16 + l15];

    f32x4 oacc[4][4];                  // [q-frag][d-frag], C: col=q, row=d
    f32x4 oextra[4];                   // ones.P^T -> every row = sum(p) for q=l15
    #pragma unroll
    for (int i = 0; i < 4; i++) {
        oextra[i] = fzero;
        #pragma unroll
        for (int f = 0; f < 4; f++) oacc[i][f] = fzero;
    }

    // stage K/V tile kt into LDS buffer bsel.  K rows permuted:
    // lds row m=(f<<4)|(qh<<2)|r  holds global key 32*(r>>1)+qh*8+2f+(r&1)
    auto stage = [&](int kt, int bsel) {
        #pragma unroll
        for (int r = 0; r < 2; r++) {
            int g = r * 256 + t, row = g >> 3, cw = g & 7;
            int swz = (cw ^ (row & 7)) * 8;
            int gk = ((row & 2) << 4) | (((row >> 2) & 3) << 3) | ((row >> 4) << 1) | (row & 1);
            gld_lds16(Kb + (size_t)kt * 64 * HD + gk * HD + swz, &Kl[bsel][g * 8]);
            gld_lds16(Vb + (size_t)row * SEQ + kt * 64 + swz, &Vl[bsel][g * 8]);
        }
    };

    auto compute = [&](int kt) {
        const u16* kbuf = &Kl[kt & 3][0];
        const u16* vbuf = &Vl[kt & 3][0];
        bf16x8 ak[2][4], av[2][4];
        #pragma unroll
        for (int f = 0; f < 4; f++) {
            ak[0][f] = *(const bf16x8*)(kbuf + kf0 + f * 1024);
            ak[1][f] = *(const bf16x8*)(kbuf + kf1 + f * 1024);
            av[0][f] = *(const bf16x8*)(vbuf + kf0 + f * 1024);
            av[1][f] = *(const bf16x8*)(vbuf + kf1 + f * 1024);
        }

        #pragma unroll
        for (int i = 0; i < 4; i++) {
            // ---- QK^T: C[m=key_lds][n=q]; key_lds row-permute makes the
            //      exp2+pack output BE the PV B-fragment (no cross-lane) ----
            f32x4 sf[4];
            __builtin_amdgcn_s_setprio(1);
            #pragma unroll
            for (int f = 0; f < 4; f++) {
                sf[f] = __builtin_amdgcn_mfma_f32_16x16x32_bf16(ak[0][f], qf[i][0], fzero, 0, 0, 0);
                sf[f] = __builtin_amdgcn_mfma_f32_16x16x32_bf16(ak[1][f], qf[i][1], sf[f], 0, 0, 0);
            }
            __builtin_amdgcn_s_setprio(0);

            // ---- exp2 -> bf16 words: word f of bp0 = keys qh*8+2f+{0,1},
            //      word f of bp1 = keys 32+qh*8+2f+{0,1}  (by construction) ----
            unsigned int w0[4], w1[4];
            #pragma unroll
            for (int f = 0; f < 4; f++) {
                w0[f] = pkbf(exp2fast(sf[f][0]), exp2fast(sf[f][1]));
                w1[f] = pkbf(exp2fast(sf[f][2]), exp2fast(sf[f][3]));
            }
            bf16x8 bp0, bp1;
            { u32x4 u = {w0[0], w0[1], w0[2], w0[3]}; __builtin_memcpy(&bp0, &u, 16); }
            { u32x4 u = {w1[0], w1[1], w1[2], w1[3]}; __builtin_memcpy(&bp1, &u, 16); }

            // ---- PV + ones row-sum ----
            __builtin_amdgcn_s_setprio(1);
            #pragma unroll
            for (int f = 0; f < 4; f++) {
                oacc[i][f] = __builtin_amdgcn_mfma_f32_16x16x32_bf16(av[0][f], bp0, oacc[i][f], 0, 0, 0);
                oacc[i][f] = __builtin_amdgcn_mfma_f32_16x16x32_bf16(av[1][f], bp1, oacc[i][f], 0, 0, 0);
            }
            oextra[i] = __builtin_amdgcn_mfma_f32_16x16x32_bf16(ones, bp0, oextra[i], 0, 0, 0);
            oextra[i] = __builtin_amdgcn_mfma_f32_16x16x32_bf16(ones, bp1, oextra[i], 0, 0, 0);
            __builtin_amdgcn_s_setprio(0);
        }
    };

    // prologue: 2-deep prefetch
    stage(0, 0);
    stage(1, 1);

    // main loop: stage(kt+2) -> counted wait for stage(kt) -> barrier -> compute
    for (int kt = 0; kt < 30; ++kt) {
        stage(kt + 2, (kt + 2) & 3);
        asm volatile("s_waitcnt vmcnt(16)" ::: "memory");   // 16 outstanding = kt+1, kt+2
        __builtin_amdgcn_s_barrier();
        compute(kt);
    }
    // kt = 30: only kt+1's 8 loads outstanding
    asm volatile("s_waitcnt vmcnt(8)" ::: "memory");
    __builtin_amdgcn_s_barrier();
    compute(30);
    // kt = 31
    asm volatile("s_waitcnt vmcnt(0)" ::: "memory");
    __builtin_amdgcn_s_barrier();
    compute(31);

    // epilogue: O^T C-layout -> Oc[b][s][h][d]; d contiguous over regs
    #pragma unroll
    for (int i = 0; i < 4; i++) {
        float inv = 1.0f / oextra[i][0];
        int s = q0 + i * 16 + l15;
        size_t base = ((size_t)(b * SEQ + s) * NH + h) * HD;
        #pragma unroll
        for (int f = 0; f < 4; f++) {
            uint2 o = { pkbf(oacc[i][f][0] * inv, oacc[i][f][1] * inv),
                        pkbf(oacc[i][f][2] * inv, oacc[i][f][3] * inv) };
            *(uint2*)&Oc[base + f * 16 + quad * 4] = o;
        }
    }
}

// ---------------------------------------------------------------------------
// Kernel 4: output projection.  out[8192,1024] = Oc @ WoT^T + bo  (fp32 out)
// ---------------------------------------------------------------------------
__global__ __launch_bounds__(256) void gemm_out(
    const u16* __restrict__ A, const u16* __restrict__ WT,
    const float* __restrict__ bo, float* __restrict__ out)
{
    __shared__ u16 Al[128 * 32];
    __shared__ u16 Bl[128 * 32];
    const int t = threadIdx.x, lane = t & 63, w = t >> 6;
    const int quad = lane >> 4, l15 = lane & 15;
    const int wr = w >> 1, wc = w & 1;
    const int m0 = blockIdx.x * 128, n0 = blockIdx.y * 128;
    const f32x4 fzero = {0.f, 0.f, 0.f, 0.f};

    f32x4 acc[4][4];
    #pragma unroll
    for (int i = 0; i < 4; i++)
        #pragma unroll
        for (int j = 0; j < 4; j++) acc[i][j] = fzero;

    for (int kt = 0; kt < 32; ++kt) {
        #pragma unroll
        for (int r = 0; r < 2; r++) {
            int g = r * 256 + t; int row = g >> 2, cw = g & 3;
            int sc = (cw ^ ((row >> 1) & 3)) * 8;
            gld_lds16(A  + (size_t)(m0 + row) * EMB + kt * 32 + sc, &Al[g * 8]);
            gld_lds16(WT + (size_t)(n0 + row) * EMB + kt * 32 + sc, &Bl[g * 8]);
        }
        __syncthreads();
        bf16x8 af[4], bfr[4];
        #pragma unroll
        for (int i = 0; i < 4; i++) {
            int rowA = wr * 64 + i * 16 + l15;
            af[i] = *(const bf16x8*)&Al[rowA * 32 + ((quad ^ ((rowA >> 1) & 3)) * 8)];
        }
        #pragma unroll
        for (int j = 0; j < 4; j++) {
            int rowB = wc * 64 + j * 16 + l15;
            bfr[j] = *(const bf16x8*)&Bl[rowB * 32 + ((quad ^ ((rowB >> 1) & 3)) * 8)];
        }
        #pragma unroll
        for (int i = 0; i < 4; i++)
            #pragma unroll
            for (int j = 0; j < 4; j++)
                acc[i][j] = __builtin_amdgcn_mfma_f32_16x16x32_bf16(af[i], bfr[j], acc[i][j], 0, 0, 0);
        __syncthreads();
    }

    #pragma unroll
    for (int j = 0; j < 4; j++) {
        int n = n0 + wc * 64 + j * 16 + l15;
        float bvl = bo[n];
        #pragma unroll
        for (int i = 0; i < 4; i++) {
            int m = m0 + wr * 64 + i * 16 + quad * 4;
            #pragma unroll
            for (int r = 0; r < 4; r++)
                out[(size_t)(m + r) * EMB + n] = acc[i][j][r] + bvl;
        }
    }
}

// ---------------------------------------------------------------------------
extern "C" void kernel_launch(void* const* d_in, const int* in_sizes, int n_in,
                              void* d_out, int out_size, void* d_ws, size_t ws_size,
                              hipStream_t stream)
{
    (void)in_sizes; (void)n_in; (void)out_size; (void)ws_size;
    const float* x  = (const float*)d_in[0];
    const float* Wq = (const float*)d_in[1];
    const float* bq = (const float*)d_in[2];
    const float* Wk = (const float*)d_in[3];
    const float* bk = (const float*)d_in[4];
    const float* Wv = (const float*)d_in[5];
    const float* bv = (const float*)d_in[6];
    const float* Wo = (const float*)d_in[7];
    const float* bo = (const float*)d_in[8];
    u16* ws = (u16*)d_ws;
    u16* Xb = (u16*)d_out;   // bf16 copy of x lives in d_out until gemm_out runs

    convert_x<<<dim3(8192), 256, 0, stream>>>(x, Xb);
    transpose_w<<<dim3(16, 16, 4), 256, 0, stream>>>(Wq, Wk, Wv, Wo, ws);
    gemm_qkv<<<dim3(64, 24), 256, 0, stream>>>(Xb, ws + OFF_WT, bq, bk, bv,
                                               ws + OFF_Q, ws + OFF_K, ws + OFF_VT);
    flash_attn<<<dim3(512), 256, 0, stream>>>(ws + OFF_Q, ws + OFF_K,
                                              ws + OFF_VT, ws + OFF_OC);
    gemm_out<<<dim3(64, 8), 256, 0, stream>>>(ws + OFF_OC, ws + OFF_WOT, bo, (float*)d_out);
}